// Round 16
// baseline (71.604 us; speedup 1.0000x reference)
//
#include <hip/hip_runtime.h>
#include <stdint.h>

#define BATCH 8
#define LTOK 1024
#define DMODEL 512
#define NHEAD 8
#define DHEAD 64

typedef unsigned short u16;
typedef u16 u16x4 __attribute__((ext_vector_type(4)));
typedef u16 u16x8 __attribute__((ext_vector_type(8)));
typedef short bf16x8 __attribute__((ext_vector_type(8)));
typedef float f32x4 __attribute__((ext_vector_type(4)));

#define MFMA16(a,b,c) __builtin_amdgcn_mfma_f32_16x16x32_bf16((a),(b),(c),0,0,0)

__device__ __forceinline__ float bf2f(u16 x){
  union{unsigned u; float f;} v; v.u = ((unsigned)x)<<16; return v.f;
}
__device__ __forceinline__ u16 f2bf(float f){
  union{float f; unsigned u;} v; v.f = f;
  unsigned r = v.u + 0x7fffu + ((v.u>>16)&1u);
  return (u16)(r>>16);
}

__device__ __forceinline__ void gload_lds16(const u16* g, u16* l){
  __builtin_amdgcn_global_load_lds(
      (const __attribute__((address_space(1))) void*)g,
      (__attribute__((address_space(3))) void*)l,
      16, 0, 0);
}

// ---------------- prep: transpose q (0..1023) + convert wqkv row-major (1024..1151)
// ---------------- + convert fc_w FRAGMENT-MAJOR (1152..1279) --------------------
// Wf[nt*8+kt][frag=ks*4+fnj][lane=lg*16+lr][j] holds W[nt*64+fnj*16+lr][kt*64+ks*32+lg*8+j]
__global__ __launch_bounds__(256) void prep_k(const float* __restrict__ q,
                                              u16* __restrict__ x_rm,
                                              const float* __restrict__ w0,
                                              u16* __restrict__ d0,
                                              const float* __restrict__ w1,
                                              u16* __restrict__ d1){
  __shared__ __align__(16) u16 t[64][72];
  const int blk = blockIdx.x;
  const int tid = threadIdx.x;
  if (blk < 1024){
    const int bx = blk & 7, by = (blk>>3) & 15, bz = blk>>7;
    const int r0 = bx*64, c0 = by*64;
    const float* s = q    + (size_t)bz*DMODEL*LTOK;
    u16* d         = x_rm + (size_t)bz*DMODEL*LTOK;
    const int row = tid>>3, ch = (tid&7)*8;
    #pragma unroll
    for (int rr=0; rr<64; rr+=32){
      const float* p = s + (size_t)(r0+row+rr)*LTOK + c0 + ch;
      u16x8 v;
      #pragma unroll
      for (int j=0;j<8;j++) v[j] = f2bf(p[j]);
      *(u16x8*)&t[row+rr][ch] = v;
    }
    __syncthreads();
    #pragma unroll
    for (int rr=0; rr<64; rr+=32){
      const int dr = row+rr;
      u16x8 v;
      #pragma unroll
      for (int j=0;j<8;j++) v[j] = t[ch+j][dr];
      *(u16x8*)(d + (size_t)(c0+dr)*DMODEL + r0 + ch) = v;
    }
  } else if (blk < 1152){
    const int b2 = blk - 1024;
    const int i = ((b2*256) + tid)*8;
    u16x8 v;
    #pragma unroll
    for (int j=0;j<8;j++) v[j] = f2bf(w0[i+j]);
    *(u16x8*)(d0 + i) = v;
  } else {
    const int b2 = blk - 1152;
    const int i = ((b2*256) + tid)*8;      // element (n,k): n=i>>9, k=i&511 (8 contig k)
    const int n = i>>9, k = i&511;
    u16x8 v;
    #pragma unroll
    for (int j=0;j<8;j++) v[j] = f2bf(w1[i+j]);
    const int nt = n>>6, kt = k>>6;
    const int dst = (nt*8 + kt)*4096 + (((k>>5)&1)*4 + ((n>>4)&3))*512
                  + (((k>>3)&3)*16 + (n&15))*8;
    *(u16x8*)(d1 + dst) = v;
  }
}

// stage a 128x64 bf16 tile into linear LDS with read-swizzle pre-applied to the
// source k-chunk (rule 21: filler granule (r, cc^(r&7)) holds A[r][cc*8])
__device__ __forceinline__ void stage128(const u16* __restrict__ src,
                                         int row0, int k0, u16* lds, int tid){
  #pragma unroll
  for (int s2=0; s2<4; ++s2){
    const int slot = tid + s2*256;
    const int row = slot>>3, ch8 = slot&7;
    const int k = k0 + ((ch8 ^ (row&7))<<3);
    gload_lds16(src + (size_t)(row0+row)*DMODEL + k, lds + slot*8);
  }
}

// ---------------- QKV projection, 128x128 tile -> frag-major K/Q and V tiles ----
__global__ __launch_bounds__(256) void qkv_gemm(const u16* __restrict__ A,
                                                const u16* __restrict__ W,
                                                u16* __restrict__ Kf,
                                                u16* __restrict__ Vf){
  __shared__ __align__(128) u16 smem[32768];
  const int m0 = blockIdx.x*128, n0 = blockIdx.y*128;
  const int tid = threadIdx.x, w = tid>>6, lane = tid&63;
  const int wr = w>>1, wc = w&1;
  const int lr = lane&15, lg = lane>>4;
  f32x4 acc[4][4] = {};
  stage128(A, m0, 0, smem, tid);
  stage128(W, n0, 0, smem + 16384, tid);
  int buf = 0;
  for (int kt=0; kt<8; ++kt){
    __syncthreads();
    if (kt < 7){
      stage128(A, m0, (kt+1)*64, smem + (buf^1)*8192, tid);
      stage128(W, n0, (kt+1)*64, smem + 16384 + (buf^1)*8192, tid);
    }
    const u16* sa = smem + buf*8192;
    const u16* sb = smem + 16384 + buf*8192;
    #pragma unroll
    for (int ks=0; ks<2; ++ks){
      bf16x8 af[4], bfr[4];
      #pragma unroll
      for (int mi=0; mi<4; ++mi){
        const int r = wr*64 + mi*16 + lr;
        af[mi] = *(const bf16x8*)(&sa[(r*64 + ks*32 + lg*8) ^ ((r&7)<<3)]);
      }
      #pragma unroll
      for (int nj=0; nj<4; ++nj){
        const int r = wc*64 + nj*16 + lr;
        bfr[nj] = *(const bf16x8*)(&sb[(r*64 + ks*32 + lg*8) ^ ((r&7)<<3)]);
      }
      #pragma unroll
      for (int mi=0; mi<4; ++mi)
        #pragma unroll
        for (int nj=0; nj<4; ++nj)
          acc[mi][nj] = MFMA16(af[mi], bfr[nj], acc[mi][nj]);
    }
    buf ^= 1;
  }
  __syncthreads();
  u16* Ktile = smem + w*4096;
  u16* Vtile = smem + 16384 + w*4096;
  #pragma unroll
  for (int mi=0; mi<4; ++mi)
    #pragma unroll
    for (int nj=0; nj<4; ++nj){
      const int rrb = mi*16 + lg*4;
      const int d   = nj*16 + lr;
      #pragma unroll
      for (int r=0; r<4; ++r){
        const int rr = rrb + r;
        Ktile[((d>>5)*4 + (rr>>4))*512 + (((d>>3)&3)*16 + (rr&15))*8 + (d&7)]
            = f2bf(acc[mi][nj][r]);
      }
      u16x4 pv;
      #pragma unroll
      for (int r=0; r<4; ++r) pv[r] = f2bf(acc[mi][nj][r]);
      *(u16x4*)&Vtile[((rrb>>5)*4 + (d>>4))*512 + (((rrb>>3)&3)*16 + (d&15))*8 + (rrb&7)] = pv;
    }
  __syncthreads();
  const int bb = m0>>10, t0 = (m0&1023)>>6, hh0 = n0>>6;
  #pragma unroll
  for (int p=0; p<8; ++p){
    const int gi = p*2048 + tid*8;
    const int lt = gi>>12, off = gi&4095;
    const size_t base = (size_t)((bb*NHEAD + hh0 + (lt&1))*16 + t0 + (lt>>1))*4096 + off;
    *(u16x8*)(Kf + base) = *(const u16x8*)(smem + gi);
    *(u16x8*)(Vf + base) = *(const u16x8*)(smem + 16384 + gi);
  }
}

// ---------------- attention: split-K (4 k-tiles/wave), L2-direct, tree merge ----
__global__ __launch_bounds__(256,2) void attn_k(const u16* __restrict__ kf,
                                                const u16* __restrict__ vf,
                                                u16* __restrict__ ao){
  __shared__ __align__(16) u16 sPm[16640];
  const int bid = blockIdx.x;
  const int qt = bid >> 6, bh = bid & 63;     // XCD = bid%8 = bh%8 -> K/V L2-resident
  const int b = bh >> 3, h = bh & 7;
  const u16* Kf = kf + (size_t)bh*16*4096;
  const u16* Vf = vf + (size_t)bh*16*4096;
  const int tid = threadIdx.x, w = tid>>6, lane = tid&63;
  const int lr = lane&15, lg = lane>>4;

  bf16x8 aq[4][2];
  #pragma unroll
  for (int g=0; g<4; ++g)
    #pragma unroll
    for (int ks=0; ks<2; ++ks){
      u16x8 v = *(const u16x8*)(Kf + (size_t)qt*4096 + (ks*4+g)*512 + lane*8);
      bf16x8 t;
      #pragma unroll
      for (int j=0;j<8;j++) t[j] = (short)f2bf(bf2f(v[j])*0.18033688f);
      aq[g][ks] = t;
    }

  f32x4 o[4][4] = {};
  float lsum[4][4] = {};

  for (int t=0; t<4; ++t){
    const int kt = w + t*4;
    const u16* Kt = Kf + (size_t)kt*4096;
    const u16* Vt = Vf + (size_t)kt*4096;
    bf16x8 bk[2][4];
    #pragma unroll
    for (int ks=0; ks<2; ++ks)
      #pragma unroll
      for (int nj=0; nj<4; ++nj)
        bk[ks][nj] = *(const bf16x8*)(Kt + (ks*4+nj)*512 + lane*8);
    #pragma unroll
    for (int g=0; g<4; ++g){
      f32x4 sc[4] = {};
      __builtin_amdgcn_s_setprio(1);
      #pragma unroll
      for (int ks=0; ks<2; ++ks)
        #pragma unroll
        for (int nj=0; nj<4; ++nj)
          sc[nj] = MFMA16(aq[g][ks], bk[ks][nj], sc[nj]);
      __builtin_amdgcn_s_setprio(0);
      const int wp = (w*4+g)*1024;
      #pragma unroll
      for (int nj=0; nj<4; ++nj){
        #pragma unroll
        for (int r=0; r<4; ++r){
          const float p = __builtin_amdgcn_exp2f(sc[nj][r]);
          lsum[g][r] += p;
          const int prow = lg*4 + r;
          sPm[wp + ((prow*64 + nj*16 + lr) ^ ((prow&7)<<3))]
              = (u16)(__float_as_uint(p)>>16);
        }
      }
    }
    asm volatile("s_waitcnt lgkmcnt(0)" ::: "memory");
    bf16x8 bv[2][4];
    #pragma unroll
    for (int ks=0; ks<2; ++ks)
      #pragma unroll
      for (int dj=0; dj<4; ++dj)
        bv[ks][dj] = *(const bf16x8*)(Vt + (ks*4+dj)*512 + lane*8);
    __builtin_amdgcn_s_setprio(1);
    #pragma unroll
    for (int g=0; g<4; ++g){
      const int wp = (w*4+g)*1024;
      #pragma unroll
      for (int ks=0; ks<2; ++ks){
        bf16x8 pa = *(const bf16x8*)(&sPm[wp + ((lr*64 + ks*32 + lg*8) ^ ((lr&7)<<3))]);
        #pragma unroll
        for (int dj=0; dj<4; ++dj)
          o[g][dj] = MFMA16(pa, bv[ks][dj], o[g][dj]);
      }
    }
    __builtin_amdgcn_s_setprio(0);
  }

  #pragma unroll
  for (int g=0; g<4; ++g)
    #pragma unroll
    for (int r=0; r<4; ++r){
      float s = lsum[g][r];
      s += __shfl_xor(s,1); s += __shfl_xor(s,2);
      s += __shfl_xor(s,4); s += __shfl_xor(s,8);
      lsum[g][r] = s;
    }

  __syncthreads();
  float* mrg = (float*)sPm;
  if (w & 1){
    float* R = mrg + (w>>1)*4160;
    #pragma unroll
    for (int g=0; g<4; ++g){
      #pragma unroll
      for (int dj=0; dj<4; ++dj)
        *(f32x4*)&R[(g*4+dj)*256 + lane*4] = o[g][dj];
      if (lr == 0)
        #pragma unroll
        for (int r=0; r<4; ++r) R[4096 + g*16 + lg*4 + r] = lsum[g][r];
    }
  }
  __syncthreads();
  if (!(w & 1)){
    float* R = mrg + (w>>1)*4160;
    #pragma unroll
    for (int g=0; g<4; ++g){
      #pragma unroll
      for (int dj=0; dj<4; ++dj)
        o[g][dj] += *(const f32x4*)&R[(g*4+dj)*256 + lane*4];
      #pragma unroll
      for (int r=0; r<4; ++r) lsum[g][r] += R[4096 + g*16 + lg*4 + r];
    }
  }
  if (w == 2){
    float* R = mrg + 4160;
    #pragma unroll
    for (int g=0; g<4; ++g){
      #pragma unroll
      for (int dj=0; dj<4; ++dj)
        *(f32x4*)&R[(g*4+dj)*256 + lane*4] = o[g][dj];
      if (lr == 0)
        #pragma unroll
        for (int r=0; r<4; ++r) R[4096 + g*16 + lg*4 + r] = lsum[g][r];
    }
  }
  __syncthreads();
  if (w == 0){
    float* R = mrg + 4160;
    #pragma unroll
    for (int g=0; g<4; ++g){
      #pragma unroll
      for (int dj=0; dj<4; ++dj)
        o[g][dj] += *(const f32x4*)&R[(g*4+dj)*256 + lane*4];
      #pragma unroll
      for (int r=0; r<4; ++r) lsum[g][r] += R[4096 + g*16 + lg*4 + r];
    }
    #pragma unroll
    for (int g=0; g<4; ++g){
      float inv[4];
      #pragma unroll
      for (int r=0; r<4; ++r) inv[r] = __builtin_amdgcn_rcpf(lsum[g][r]);
      const int i0 = qt*64 + g*16;
      #pragma unroll
      for (int dj=0; dj<4; ++dj)
        #pragma unroll
        for (int r=0; r<4; ++r){
          const int l = i0 + lg*4 + r;
          const int d = dj*16 + lr;
          ao[((size_t)(b*LTOK + l))*DMODEL + h*DHEAD + d] = f2bf(o[g][dj][r]*inv[r]);
        }
    }
  }
}

// ---------------- FC (M=32 x N=512 full-width) + bias + residual + LayerNorm ----
// A staged LDS dbuf; W fragment-major direct from L2; LN fused on full rows.
__global__ __launch_bounds__(256,2) void fc_ln(const u16* __restrict__ A,
                                               const u16* __restrict__ Wf,
                                               const float* __restrict__ bias,
                                               const u16* __restrict__ resid,
                                               const float* __restrict__ gamma,
                                               const float* __restrict__ beta,
                                               float* __restrict__ out){
  __shared__ __align__(128) u16 sA[2][2048];    // 32x64 dbuf
  __shared__ __align__(16)  u16 sY[32*520];     // y stage, padded rows
  const int m0 = blockIdx.x*32;
  const int tid = threadIdx.x, w = tid>>6, lane = tid&63;
  const int lr = lane&15, lg = lane>>4;

  f32x4 acc[2][8] = {};
  // prologue stage kt=0
  {
    const int row = tid>>3, ch8 = tid&7;
    gload_lds16(A + (size_t)(m0+row)*DMODEL + ((ch8 ^ (row&7))<<3), sA[0] + tid*8);
  }
  int buf = 0;
  for (int kt=0; kt<8; ++kt){
    __syncthreads();
    if (kt < 7){
      const int row = tid>>3, ch8 = tid&7;
      gload_lds16(A + (size_t)(m0+row)*DMODEL + (kt+1)*64 + ((ch8 ^ (row&7))<<3),
                  sA[buf^1] + tid*8);
    }
    // B fragments for this k-tile: wave strip cols w*128..+127
    bf16x8 bfr[2][8];
    #pragma unroll
    for (int ks=0; ks<2; ++ks)
      #pragma unroll
      for (int nj=0; nj<8; ++nj){
        const int nt = w*2 + (nj>>2);
        bfr[ks][nj] = *(const bf16x8*)(Wf + (size_t)(nt*8 + kt)*4096
                                       + (ks*4 + (nj&3))*512 + lane*8);
      }
    #pragma unroll
    for (int ks=0; ks<2; ++ks){
      bf16x8 af[2];
      #pragma unroll
      for (int mi=0; mi<2; ++mi){
        const int r = mi*16 + lr;
        af[mi] = *(const bf16x8*)(&sA[buf][(r*64 + ks*32 + lg*8) ^ ((r&7)<<3)]);
      }
      #pragma unroll
      for (int mi=0; mi<2; ++mi)
        #pragma unroll
        for (int nj=0; nj<8; ++nj)
          acc[mi][nj] = MFMA16(af[mi], bfr[ks][nj], acc[mi][nj]);
    }
    buf ^= 1;
  }
  __syncthreads();
  // stage y (bf16) into padded LDS rows
  #pragma unroll
  for (int mi=0; mi<2; ++mi)
    #pragma unroll
    for (int nj=0; nj<8; ++nj){
      const int d = w*128 + nj*16 + lr;
      #pragma unroll
      for (int r=0; r<4; ++r){
        const int rr = mi*16 + lg*4 + r;
        sY[rr*520 + d] = f2bf(acc[mi][nj][r]);
      }
    }
  __syncthreads();
  // LN: wave w handles rows w*8..w*8+7; fully coalesced resid/bias/gamma/beta
  const float g0a = gamma[lane*8+0], g1 = gamma[lane*8+1], g2 = gamma[lane*8+2],
              g3 = gamma[lane*8+3], g4 = gamma[lane*8+4], g5 = gamma[lane*8+5],
              g6 = gamma[lane*8+6], g7 = gamma[lane*8+7];
  const float b0 = beta[lane*8+0], b1 = beta[lane*8+1], b2 = beta[lane*8+2],
              b3 = beta[lane*8+3], b4 = beta[lane*8+4], b5 = beta[lane*8+5],
              b6 = beta[lane*8+6], b7 = beta[lane*8+7];
  const float bi0 = bias[lane*8+0], bi1 = bias[lane*8+1], bi2 = bias[lane*8+2],
              bi3 = bias[lane*8+3], bi4 = bias[lane*8+4], bi5 = bias[lane*8+5],
              bi6 = bias[lane*8+6], bi7 = bias[lane*8+7];
  const float gm[8] = {g0a,g1,g2,g3,g4,g5,g6,g7};
  const float bt[8] = {b0,b1,b2,b3,b4,b5,b6,b7};
  const float bi[8] = {bi0,bi1,bi2,bi3,bi4,bi5,bi6,bi7};
  #pragma unroll
  for (int i=0; i<8; ++i){
    const int rr = w*8 + i;
    u16x8 yv = *(const u16x8*)&sY[rr*520 + lane*8];
    u16x8 rv = *(const u16x8*)(resid + (size_t)(m0+rr)*DMODEL + lane*8);
    float x[8]; float s=0.f, sq=0.f;
    #pragma unroll
    for (int j=0;j<8;j++){
      x[j] = bf2f(yv[j]) + bi[j] + bf2f(rv[j]);
      s += x[j]; sq += x[j]*x[j];
    }
    #pragma unroll
    for (int mk=1; mk<64; mk<<=1){ s += __shfl_xor(s,mk); sq += __shfl_xor(sq,mk); }
    const float mean = s*(1.f/DMODEL);
    const float var = sq*(1.f/DMODEL) - mean*mean;
    const float rstd = rsqrtf(var + 1e-5f);
    float* po = out + (size_t)(m0+rr)*DMODEL + lane*8;
    #pragma unroll
    for (int j=0;j<8;j++) po[j] = (x[j]-mean)*rstd*gm[j] + bt[j];
  }
}

extern "C" void kernel_launch(void* const* d_in, const int* in_sizes, int n_in,
                              void* d_out, int out_size, void* d_ws, size_t ws_size,
                              hipStream_t stream){
  (void)in_sizes; (void)n_in; (void)out_size; (void)ws_size;
  const float* q      = (const float*)d_in[0];
  const float* w_qkvs = (const float*)d_in[1];
  const float* fc_w   = (const float*)d_in[2];
  const float* fc_b   = (const float*)d_in[3];
  const float* ln_g   = (const float*)d_in[4];
  const float* ln_b   = (const float*)d_in[5];
  float* out = (float*)d_out;
  char* ws = (char*)d_ws;
  u16* x_rm  = (u16*)(ws);                 // [8192][512] bf16
  u16* kfb   = (u16*)(ws + 8388608);       // fragment-major K/Q tiles
  u16* vfb   = (u16*)(ws + 16777216);      // fragment-major V tiles
  u16* ao    = (u16*)(ws + 25165824);      // [8192][512]
  u16* wqkvb = (u16*)(ws + 33554432);      // row-major bf16
  u16* wfcf  = (u16*)(ws + 34078720);      // fragment-major bf16

  prep_k<<<1280,256,0,stream>>>(q, x_rm, w_qkvs, wqkvb, fc_w, wfcf);
  qkv_gemm<<<dim3(64,4),256,0,stream>>>(x_rm, wqkvb, kfb, vfb);
  attn_k<<<1024,256,0,stream>>>(kfb, vfb, ao);
  fc_ln<<<256,256,0,stream>>>(ao, wfcf, fc_b, x_rm, ln_g, ln_b, out);
}

// Round 17
// 69.384 us; speedup vs baseline: 1.0320x; 1.0320x over previous
//
#include <hip/hip_runtime.h>
#include <stdint.h>

#define BATCH 8
#define LTOK 1024
#define DMODEL 512
#define NHEAD 8
#define DHEAD 64

typedef unsigned short u16;
typedef u16 u16x4 __attribute__((ext_vector_type(4)));
typedef u16 u16x8 __attribute__((ext_vector_type(8)));
typedef short bf16x8 __attribute__((ext_vector_type(8)));
typedef float f32x4 __attribute__((ext_vector_type(4)));

#define MFMA16(a,b,c) __builtin_amdgcn_mfma_f32_16x16x32_bf16((a),(b),(c),0,0,0)

__device__ __forceinline__ float bf2f(u16 x){
  union{unsigned u; float f;} v; v.u = ((unsigned)x)<<16; return v.f;
}
__device__ __forceinline__ u16 f2bf(float f){
  union{float f; unsigned u;} v; v.f = f;
  unsigned r = v.u + 0x7fffu + ((v.u>>16)&1u);
  return (u16)(r>>16);
}

__device__ __forceinline__ void gload_lds16(const u16* g, u16* l){
  __builtin_amdgcn_global_load_lds(
      (const __attribute__((address_space(1))) void*)g,
      (__attribute__((address_space(3))) void*)l,
      16, 0, 0);
}

// ---------------- prep: transpose q (0..1023) + convert wqkv row-major (1024..1151)
// ---------------- + convert fc_w FRAGMENT-MAJOR (1152..1279) --------------------
// Wf[nt*8+kt][frag=ks*4+fnj][lane=lg*16+lr][j] holds W[nt*64+fnj*16+lr][kt*64+ks*32+lg*8+j]
__global__ __launch_bounds__(256) void prep_k(const float* __restrict__ q,
                                              u16* __restrict__ x_rm,
                                              const float* __restrict__ w0,
                                              u16* __restrict__ d0,
                                              const float* __restrict__ w1,
                                              u16* __restrict__ d1){
  __shared__ __align__(16) u16 t[64][72];
  const int blk = blockIdx.x;
  const int tid = threadIdx.x;
  if (blk < 1024){
    const int bx = blk & 7, by = (blk>>3) & 15, bz = blk>>7;
    const int r0 = bx*64, c0 = by*64;
    const float* s = q    + (size_t)bz*DMODEL*LTOK;
    u16* d         = x_rm + (size_t)bz*DMODEL*LTOK;
    const int row = tid>>3, ch = (tid&7)*8;
    #pragma unroll
    for (int rr=0; rr<64; rr+=32){
      const float* p = s + (size_t)(r0+row+rr)*LTOK + c0 + ch;
      u16x8 v;
      #pragma unroll
      for (int j=0;j<8;j++) v[j] = f2bf(p[j]);
      *(u16x8*)&t[row+rr][ch] = v;
    }
    __syncthreads();
    #pragma unroll
    for (int rr=0; rr<64; rr+=32){
      const int dr = row+rr;
      u16x8 v;
      #pragma unroll
      for (int j=0;j<8;j++) v[j] = t[ch+j][dr];
      *(u16x8*)(d + (size_t)(c0+dr)*DMODEL + r0 + ch) = v;
    }
  } else if (blk < 1152){
    const int b2 = blk - 1024;
    const int i = ((b2*256) + tid)*8;
    u16x8 v;
    #pragma unroll
    for (int j=0;j<8;j++) v[j] = f2bf(w0[i+j]);
    *(u16x8*)(d0 + i) = v;
  } else {
    const int b2 = blk - 1152;
    const int i = ((b2*256) + tid)*8;      // element (n,k): n=i>>9, k=i&511 (8 contig k)
    const int n = i>>9, k = i&511;
    u16x8 v;
    #pragma unroll
    for (int j=0;j<8;j++) v[j] = f2bf(w1[i+j]);
    const int nt = n>>6, kt = k>>6;
    const int dst = (nt*8 + kt)*4096 + (((k>>5)&1)*4 + ((n>>4)&3))*512
                  + (((k>>3)&3)*16 + (n&15))*8;
    *(u16x8*)(d1 + dst) = v;
  }
}

// stage a 128x64 bf16 tile into linear LDS with read-swizzle pre-applied to the
// source k-chunk (rule 21: filler granule (r, cc^(r&7)) holds A[r][cc*8])
__device__ __forceinline__ void stage128(const u16* __restrict__ src,
                                         int row0, int k0, u16* lds, int tid){
  #pragma unroll
  for (int s2=0; s2<4; ++s2){
    const int slot = tid + s2*256;
    const int row = slot>>3, ch8 = slot&7;
    const int k = k0 + ((ch8 ^ (row&7))<<3);
    gload_lds16(src + (size_t)(row0+row)*DMODEL + k, lds + slot*8);
  }
}

// ---------------- QKV projection, 128x128 tile -> frag-major K/Q and V tiles ----
__global__ __launch_bounds__(256) void qkv_gemm(const u16* __restrict__ A,
                                                const u16* __restrict__ W,
                                                u16* __restrict__ Kf,
                                                u16* __restrict__ Vf){
  __shared__ __align__(128) u16 smem[32768];
  const int m0 = blockIdx.x*128, n0 = blockIdx.y*128;
  const int tid = threadIdx.x, w = tid>>6, lane = tid&63;
  const int wr = w>>1, wc = w&1;
  const int lr = lane&15, lg = lane>>4;
  f32x4 acc[4][4] = {};
  stage128(A, m0, 0, smem, tid);
  stage128(W, n0, 0, smem + 16384, tid);
  int buf = 0;
  for (int kt=0; kt<8; ++kt){
    __syncthreads();
    if (kt < 7){
      stage128(A, m0, (kt+1)*64, smem + (buf^1)*8192, tid);
      stage128(W, n0, (kt+1)*64, smem + 16384 + (buf^1)*8192, tid);
    }
    const u16* sa = smem + buf*8192;
    const u16* sb = smem + 16384 + buf*8192;
    #pragma unroll
    for (int ks=0; ks<2; ++ks){
      bf16x8 af[4], bfr[4];
      #pragma unroll
      for (int mi=0; mi<4; ++mi){
        const int r = wr*64 + mi*16 + lr;
        af[mi] = *(const bf16x8*)(&sa[(r*64 + ks*32 + lg*8) ^ ((r&7)<<3)]);
      }
      #pragma unroll
      for (int nj=0; nj<4; ++nj){
        const int r = wc*64 + nj*16 + lr;
        bfr[nj] = *(const bf16x8*)(&sb[(r*64 + ks*32 + lg*8) ^ ((r&7)<<3)]);
      }
      #pragma unroll
      for (int mi=0; mi<4; ++mi)
        #pragma unroll
        for (int nj=0; nj<4; ++nj)
          acc[mi][nj] = MFMA16(af[mi], bfr[nj], acc[mi][nj]);
    }
    buf ^= 1;
  }
  __syncthreads();
  u16* Ktile = smem + w*4096;
  u16* Vtile = smem + 16384 + w*4096;
  #pragma unroll
  for (int mi=0; mi<4; ++mi)
    #pragma unroll
    for (int nj=0; nj<4; ++nj){
      const int rrb = mi*16 + lg*4;
      const int d   = nj*16 + lr;
      #pragma unroll
      for (int r=0; r<4; ++r){
        const int rr = rrb + r;
        Ktile[((d>>5)*4 + (rr>>4))*512 + (((d>>3)&3)*16 + (rr&15))*8 + (d&7)]
            = f2bf(acc[mi][nj][r]);
      }
      u16x4 pv;
      #pragma unroll
      for (int r=0; r<4; ++r) pv[r] = f2bf(acc[mi][nj][r]);
      *(u16x4*)&Vtile[((rrb>>5)*4 + (d>>4))*512 + (((rrb>>3)&3)*16 + (d&15))*8 + (rrb&7)] = pv;
    }
  __syncthreads();
  const int bb = m0>>10, t0 = (m0&1023)>>6, hh0 = n0>>6;
  #pragma unroll
  for (int p=0; p<8; ++p){
    const int gi = p*2048 + tid*8;
    const int lt = gi>>12, off = gi&4095;
    const size_t base = (size_t)((bb*NHEAD + hh0 + (lt&1))*16 + t0 + (lt>>1))*4096 + off;
    *(u16x8*)(Kf + base) = *(const u16x8*)(smem + gi);
    *(u16x8*)(Vf + base) = *(const u16x8*)(smem + 16384 + gi);
  }
}

// ---------------- attention: split-K (4 k-tiles/wave), L2-direct, tree merge ----
__global__ __launch_bounds__(256,2) void attn_k(const u16* __restrict__ kf,
                                                const u16* __restrict__ vf,
                                                u16* __restrict__ ao){
  __shared__ __align__(16) u16 sPm[16640];
  const int bid = blockIdx.x;
  const int qt = bid >> 6, bh = bid & 63;     // XCD = bid%8 = bh%8 -> K/V L2-resident
  const int b = bh >> 3, h = bh & 7;
  const u16* Kf = kf + (size_t)bh*16*4096;
  const u16* Vf = vf + (size_t)bh*16*4096;
  const int tid = threadIdx.x, w = tid>>6, lane = tid&63;
  const int lr = lane&15, lg = lane>>4;

  bf16x8 aq[4][2];
  #pragma unroll
  for (int g=0; g<4; ++g)
    #pragma unroll
    for (int ks=0; ks<2; ++ks){
      u16x8 v = *(const u16x8*)(Kf + (size_t)qt*4096 + (ks*4+g)*512 + lane*8);
      bf16x8 t;
      #pragma unroll
      for (int j=0;j<8;j++) t[j] = (short)f2bf(bf2f(v[j])*0.18033688f);
      aq[g][ks] = t;
    }

  f32x4 o[4][4] = {};
  float lsum[4][4] = {};

  for (int t=0; t<4; ++t){
    const int kt = w + t*4;
    const u16* Kt = Kf + (size_t)kt*4096;
    const u16* Vt = Vf + (size_t)kt*4096;
    bf16x8 bk[2][4];
    #pragma unroll
    for (int ks=0; ks<2; ++ks)
      #pragma unroll
      for (int nj=0; nj<4; ++nj)
        bk[ks][nj] = *(const bf16x8*)(Kt + (ks*4+nj)*512 + lane*8);
    #pragma unroll
    for (int g=0; g<4; ++g){
      f32x4 sc[4] = {};
      __builtin_amdgcn_s_setprio(1);
      #pragma unroll
      for (int ks=0; ks<2; ++ks)
        #pragma unroll
        for (int nj=0; nj<4; ++nj)
          sc[nj] = MFMA16(aq[g][ks], bk[ks][nj], sc[nj]);
      __builtin_amdgcn_s_setprio(0);
      const int wp = (w*4+g)*1024;
      #pragma unroll
      for (int nj=0; nj<4; ++nj){
        #pragma unroll
        for (int r=0; r<4; ++r){
          const float p = __builtin_amdgcn_exp2f(sc[nj][r]);
          lsum[g][r] += p;
          const int prow = lg*4 + r;
          sPm[wp + ((prow*64 + nj*16 + lr) ^ ((prow&7)<<3))]
              = (u16)(__float_as_uint(p)>>16);
        }
      }
    }
    asm volatile("s_waitcnt lgkmcnt(0)" ::: "memory");
    bf16x8 bv[2][4];
    #pragma unroll
    for (int ks=0; ks<2; ++ks)
      #pragma unroll
      for (int dj=0; dj<4; ++dj)
        bv[ks][dj] = *(const bf16x8*)(Vt + (ks*4+dj)*512 + lane*8);
    __builtin_amdgcn_s_setprio(1);
    #pragma unroll
    for (int g=0; g<4; ++g){
      const int wp = (w*4+g)*1024;
      #pragma unroll
      for (int ks=0; ks<2; ++ks){
        bf16x8 pa = *(const bf16x8*)(&sPm[wp + ((lr*64 + ks*32 + lg*8) ^ ((lr&7)<<3))]);
        #pragma unroll
        for (int dj=0; dj<4; ++dj)
          o[g][dj] = MFMA16(pa, bv[ks][dj], o[g][dj]);
      }
    }
    __builtin_amdgcn_s_setprio(0);
  }

  #pragma unroll
  for (int g=0; g<4; ++g)
    #pragma unroll
    for (int r=0; r<4; ++r){
      float s = lsum[g][r];
      s += __shfl_xor(s,1); s += __shfl_xor(s,2);
      s += __shfl_xor(s,4); s += __shfl_xor(s,8);
      lsum[g][r] = s;
    }

  __syncthreads();
  float* mrg = (float*)sPm;
  if (w & 1){
    float* R = mrg + (w>>1)*4160;
    #pragma unroll
    for (int g=0; g<4; ++g){
      #pragma unroll
      for (int dj=0; dj<4; ++dj)
        *(f32x4*)&R[(g*4+dj)*256 + lane*4] = o[g][dj];
      if (lr == 0)
        #pragma unroll
        for (int r=0; r<4; ++r) R[4096 + g*16 + lg*4 + r] = lsum[g][r];
    }
  }
  __syncthreads();
  if (!(w & 1)){
    float* R = mrg + (w>>1)*4160;
    #pragma unroll
    for (int g=0; g<4; ++g){
      #pragma unroll
      for (int dj=0; dj<4; ++dj)
        o[g][dj] += *(const f32x4*)&R[(g*4+dj)*256 + lane*4];
      #pragma unroll
      for (int r=0; r<4; ++r) lsum[g][r] += R[4096 + g*16 + lg*4 + r];
    }
  }
  if (w == 2){
    float* R = mrg + 4160;
    #pragma unroll
    for (int g=0; g<4; ++g){
      #pragma unroll
      for (int dj=0; dj<4; ++dj)
        *(f32x4*)&R[(g*4+dj)*256 + lane*4] = o[g][dj];
      if (lr == 0)
        #pragma unroll
        for (int r=0; r<4; ++r) R[4096 + g*16 + lg*4 + r] = lsum[g][r];
    }
  }
  __syncthreads();
  if (w == 0){
    float* R = mrg + 4160;
    #pragma unroll
    for (int g=0; g<4; ++g){
      #pragma unroll
      for (int dj=0; dj<4; ++dj)
        o[g][dj] += *(const f32x4*)&R[(g*4+dj)*256 + lane*4];
      #pragma unroll
      for (int r=0; r<4; ++r) lsum[g][r] += R[4096 + g*16 + lg*4 + r];
    }
    #pragma unroll
    for (int g=0; g<4; ++g){
      float inv[4];
      #pragma unroll
      for (int r=0; r<4; ++r) inv[r] = __builtin_amdgcn_rcpf(lsum[g][r]);
      const int i0 = qt*64 + g*16;
      #pragma unroll
      for (int dj=0; dj<4; ++dj)
        #pragma unroll
        for (int r=0; r<4; ++r){
          const int l = i0 + lg*4 + r;
          const int d = dj*16 + lr;
          ao[((size_t)(b*LTOK + l))*DMODEL + h*DHEAD + d] = f2bf(o[g][dj][r]*inv[r]);
        }
    }
  }
}

// ---------------- FC (M=32 x N=512, 8 waves) + bias + residual + LayerNorm ------
// v2: 512 threads -> 2 waves/SIMD TLP (round-16 had 1/SIMD: latency-exposed).
// Each wave owns a 32x64 strip; W frag-major direct from L2 (own strip only).
__global__ __launch_bounds__(512,1) void fc_ln(const u16* __restrict__ A,
                                               const u16* __restrict__ Wf,
                                               const float* __restrict__ bias,
                                               const u16* __restrict__ resid,
                                               const float* __restrict__ gamma,
                                               const float* __restrict__ beta,
                                               float* __restrict__ out){
  __shared__ __align__(128) u16 sA[2][2048];    // 32x64 A dbuf
  __shared__ __align__(16)  u16 sY[32*520];     // y stage, padded rows
  const int m0 = blockIdx.x*32;
  const int tid = threadIdx.x, w = tid>>6, lane = tid&63;
  const int lr = lane&15, lg = lane>>4;

  f32x4 acc[2][4] = {};
  if (tid < 256){
    const int row = tid>>3, ch8 = tid&7;
    gload_lds16(A + (size_t)(m0+row)*DMODEL + ((ch8 ^ (row&7))<<3), sA[0] + tid*8);
  }
  int buf = 0;
  for (int kt=0; kt<8; ++kt){
    __syncthreads();
    if (kt < 7 && tid < 256){
      const int row = tid>>3, ch8 = tid&7;
      gload_lds16(A + (size_t)(m0+row)*DMODEL + (kt+1)*64 + ((ch8 ^ (row&7))<<3),
                  sA[buf^1] + tid*8);
    }
    // B fragments: wave w's 64-col strip = Wf tile nt=w, k-tile kt
    bf16x8 bfr[2][4];
    #pragma unroll
    for (int ks=0; ks<2; ++ks)
      #pragma unroll
      for (int nj=0; nj<4; ++nj)
        bfr[ks][nj] = *(const bf16x8*)(Wf + (size_t)(w*8 + kt)*4096
                                       + (ks*4 + nj)*512 + lane*8);
    #pragma unroll
    for (int ks=0; ks<2; ++ks){
      bf16x8 af[2];
      #pragma unroll
      for (int mi=0; mi<2; ++mi){
        const int r = mi*16 + lr;
        af[mi] = *(const bf16x8*)(&sA[buf][(r*64 + ks*32 + lg*8) ^ ((r&7)<<3)]);
      }
      #pragma unroll
      for (int mi=0; mi<2; ++mi)
        #pragma unroll
        for (int nj=0; nj<4; ++nj)
          acc[mi][nj] = MFMA16(af[mi], bfr[ks][nj], acc[mi][nj]);
    }
    buf ^= 1;
  }
  __syncthreads();
  // stage y (bf16) into padded LDS rows; wave w covers cols w*64..+63
  #pragma unroll
  for (int mi=0; mi<2; ++mi)
    #pragma unroll
    for (int nj=0; nj<4; ++nj){
      const int d = w*64 + nj*16 + lr;
      #pragma unroll
      for (int r=0; r<4; ++r){
        const int rr = mi*16 + lg*4 + r;
        sY[rr*520 + d] = f2bf(acc[mi][nj][r]);
      }
    }
  __syncthreads();
  // LN: wave w handles rows w*4..w*4+3; fully coalesced loads, fp32 out
  float gm[8], bt[8], bi[8];
  #pragma unroll
  for (int j=0;j<8;j++){
    gm[j] = gamma[lane*8+j];
    bt[j] = beta[lane*8+j];
    bi[j] = bias[lane*8+j];
  }
  #pragma unroll
  for (int i=0; i<4; ++i){
    const int rr = w*4 + i;
    u16x8 yv = *(const u16x8*)&sY[rr*520 + lane*8];
    u16x8 rv = *(const u16x8*)(resid + (size_t)(m0+rr)*DMODEL + lane*8);
    float x[8]; float s=0.f, sq=0.f;
    #pragma unroll
    for (int j=0;j<8;j++){
      x[j] = bf2f(yv[j]) + bi[j] + bf2f(rv[j]);
      s += x[j]; sq += x[j]*x[j];
    }
    #pragma unroll
    for (int mk=1; mk<64; mk<<=1){ s += __shfl_xor(s,mk); sq += __shfl_xor(sq,mk); }
    const float mean = s*(1.f/DMODEL);
    const float var = sq*(1.f/DMODEL) - mean*mean;
    const float rstd = rsqrtf(var + 1e-5f);
    float* po = out + (size_t)(m0+rr)*DMODEL + lane*8;
    #pragma unroll
    for (int j=0;j<8;j++) po[j] = (x[j]-mean)*rstd*gm[j] + bt[j];
  }
}

extern "C" void kernel_launch(void* const* d_in, const int* in_sizes, int n_in,
                              void* d_out, int out_size, void* d_ws, size_t ws_size,
                              hipStream_t stream){
  (void)in_sizes; (void)n_in; (void)out_size; (void)ws_size;
  const float* q      = (const float*)d_in[0];
  const float* w_qkvs = (const float*)d_in[1];
  const float* fc_w   = (const float*)d_in[2];
  const float* fc_b   = (const float*)d_in[3];
  const float* ln_g   = (const float*)d_in[4];
  const float* ln_b   = (const float*)d_in[5];
  float* out = (float*)d_out;
  char* ws = (char*)d_ws;
  u16* x_rm  = (u16*)(ws);                 // [8192][512] bf16
  u16* kfb   = (u16*)(ws + 8388608);       // fragment-major K/Q tiles
  u16* vfb   = (u16*)(ws + 16777216);      // fragment-major V tiles
  u16* ao    = (u16*)(ws + 25165824);      // [8192][512]
  u16* wqkvb = (u16*)(ws + 33554432);      // row-major bf16
  u16* wfcf  = (u16*)(ws + 34078720);      // fragment-major bf16

  prep_k<<<1280,256,0,stream>>>(q, x_rm, w_qkvs, wqkvb, fc_w, wfcf);
  qkv_gemm<<<dim3(64,4),256,0,stream>>>(x_rm, wqkvb, kfb, vfb);
  attn_k<<<1024,256,0,stream>>>(kfb, vfb, ao);
  fc_ln<<<256,512,0,stream>>>(ao, wfcf, fc_b, x_rm, ln_g, ln_b, out);
}

// Round 19
// 68.929 us; speedup vs baseline: 1.0388x; 1.0066x over previous
//
#include <hip/hip_runtime.h>
#include <stdint.h>

#define BATCH 8
#define LTOK 1024
#define DMODEL 512
#define NHEAD 8
#define DHEAD 64

typedef unsigned short u16;
typedef u16 u16x4 __attribute__((ext_vector_type(4)));
typedef u16 u16x8 __attribute__((ext_vector_type(8)));
typedef short bf16x8 __attribute__((ext_vector_type(8)));
typedef float f32x4 __attribute__((ext_vector_type(4)));

#define MFMA16(a,b,c) __builtin_amdgcn_mfma_f32_16x16x32_bf16((a),(b),(c),0,0,0)

__device__ __forceinline__ float bf2f(u16 x){
  union{unsigned u; float f;} v; v.u = ((unsigned)x)<<16; return v.f;
}
__device__ __forceinline__ u16 f2bf(float f){
  union{float f; unsigned u;} v; v.f = f;
  unsigned r = v.u + 0x7fffu + ((v.u>>16)&1u);
  return (u16)(r>>16);
}

__device__ __forceinline__ void gload_lds16(const u16* g, u16* l){
  __builtin_amdgcn_global_load_lds(
      (const __attribute__((address_space(1))) void*)g,
      (__attribute__((address_space(3))) void*)l,
      16, 0, 0);
}

// ---------------- prep: transpose q (blocks 0..1023) + convert weights (1024..1279)
__global__ __launch_bounds__(256) void prep_k(const float* __restrict__ q,
                                              u16* __restrict__ x_rm,
                                              const float* __restrict__ w0,
                                              u16* __restrict__ d0,
                                              const float* __restrict__ w1,
                                              u16* __restrict__ d1){
  __shared__ __align__(16) u16 t[64][72];
  const int blk = blockIdx.x;
  const int tid = threadIdx.x;
  if (blk < 1024){
    // 64x64 tiled transpose fp32->bf16: x_rm[b][l][c] = q[b][c][l]
    const int bx = blk & 7, by = (blk>>3) & 15, bz = blk>>7;
    const int r0 = bx*64, c0 = by*64;
    const float* s = q    + (size_t)bz*DMODEL*LTOK;
    u16* d         = x_rm + (size_t)bz*DMODEL*LTOK;
    const int row = tid>>3, ch = (tid&7)*8;
    #pragma unroll
    for (int rr=0; rr<64; rr+=32){
      const float* p = s + (size_t)(r0+row+rr)*LTOK + c0 + ch;
      u16x8 v;
      #pragma unroll
      for (int j=0;j<8;j++) v[j] = f2bf(p[j]);
      *(u16x8*)&t[row+rr][ch] = v;
    }
    __syncthreads();
    #pragma unroll
    for (int rr=0; rr<64; rr+=32){
      const int dr = row+rr;
      u16x8 v;
      #pragma unroll
      for (int j=0;j<8;j++) v[j] = t[ch+j][dr];
      *(u16x8*)(d + (size_t)(c0+dr)*DMODEL + r0 + ch) = v;
    }
  } else {
    const int b2 = blk - 1024;
    const float* src = (b2 < 128) ? w0 : w1;
    u16* dst        = (b2 < 128) ? d0 : d1;
    const int i = (((b2 & 127)*256) + tid)*8;
    u16x8 v;
    #pragma unroll
    for (int j=0;j<8;j++) v[j] = f2bf(src[i+j]);
    *(u16x8*)(dst + i) = v;
  }
}

// stage a 128x64 bf16 tile into linear LDS with read-swizzle pre-applied to the
// source k-chunk (rule 21: filler granule (r, cc^(r&7)) holds A[r][cc*8])
__device__ __forceinline__ void stage128(const u16* __restrict__ src,
                                         int row0, int k0, u16* lds, int tid){
  #pragma unroll
  for (int s2=0; s2<4; ++s2){
    const int slot = tid + s2*256;
    const int row = slot>>3, ch8 = slot&7;
    const int k = k0 + ((ch8 ^ (row&7))<<3);
    gload_lds16(src + (size_t)(row0+row)*DMODEL + k, lds + slot*8);
  }
}

// ---------------- QKV projection, 128x128 tile -> frag-major K/Q and V tiles ----
// Kf[bh][t][frag=ks*4+nj][lane=lg*16+lr][j]  holds K[t*64+nj*16+lr][ks*32+lg*8+j]
// Vf[bh][t][frag=ks*4+dj][lane=lg*16+lr][j]  holds V[t*64+ks*32+lg*8+j][dj*16+lr]
__global__ __launch_bounds__(256) void qkv_gemm(const u16* __restrict__ A,
                                                const u16* __restrict__ W,
                                                u16* __restrict__ Kf,
                                                u16* __restrict__ Vf){
  __shared__ __align__(128) u16 smem[32768];   // 64KB arena: A dbuf 32K | B dbuf 32K
  const int m0 = blockIdx.x*128, n0 = blockIdx.y*128;
  const int tid = threadIdx.x, w = tid>>6, lane = tid&63;
  const int wr = w>>1, wc = w&1;
  const int lr = lane&15, lg = lane>>4;
  f32x4 acc[4][4] = {};
  stage128(A, m0, 0, smem, tid);
  stage128(W, n0, 0, smem + 16384, tid);
  int buf = 0;
  for (int kt=0; kt<8; ++kt){
    __syncthreads();
    if (kt < 7){
      stage128(A, m0, (kt+1)*64, smem + (buf^1)*8192, tid);
      stage128(W, n0, (kt+1)*64, smem + 16384 + (buf^1)*8192, tid);
    }
    const u16* sa = smem + buf*8192;
    const u16* sb = smem + 16384 + buf*8192;
    #pragma unroll
    for (int ks=0; ks<2; ++ks){
      bf16x8 af[4], bfr[4];
      #pragma unroll
      for (int mi=0; mi<4; ++mi){
        const int r = wr*64 + mi*16 + lr;
        af[mi] = *(const bf16x8*)(&sa[(r*64 + ks*32 + lg*8) ^ ((r&7)<<3)]);
      }
      #pragma unroll
      for (int nj=0; nj<4; ++nj){
        const int r = wc*64 + nj*16 + lr;
        bfr[nj] = *(const bf16x8*)(&sb[(r*64 + ks*32 + lg*8) ^ ((r&7)<<3)]);
      }
      #pragma unroll
      for (int mi=0; mi<4; ++mi)
        #pragma unroll
        for (int nj=0; nj<4; ++nj)
          acc[mi][nj] = MFMA16(af[mi], bfr[nj], acc[mi][nj]);
    }
    buf ^= 1;
  }
  __syncthreads();                 // final compute read smem[1]/[3]; arena now free
  u16* Ktile = smem + w*4096;
  u16* Vtile = smem + 16384 + w*4096;
  #pragma unroll
  for (int mi=0; mi<4; ++mi)
    #pragma unroll
    for (int nj=0; nj<4; ++nj){
      const int rrb = mi*16 + lg*4;
      const int d   = nj*16 + lr;
      #pragma unroll
      for (int r=0; r<4; ++r){
        const int rr = rrb + r;
        Ktile[((d>>5)*4 + (rr>>4))*512 + (((d>>3)&3)*16 + (rr&15))*8 + (d&7)]
            = f2bf(acc[mi][nj][r]);
      }
      u16x4 pv;
      #pragma unroll
      for (int r=0; r<4; ++r) pv[r] = f2bf(acc[mi][nj][r]);
      *(u16x4*)&Vtile[((rrb>>5)*4 + (d>>4))*512 + (((rrb>>3)&3)*16 + (d&15))*8 + (rrb&7)] = pv;
    }
  __syncthreads();
  const int bb = m0>>10, t0 = (m0&1023)>>6, hh0 = n0>>6;
  #pragma unroll
  for (int p=0; p<8; ++p){
    const int gi = p*2048 + tid*8;
    const int lt = gi>>12, off = gi&4095;
    const size_t base = (size_t)((bb*NHEAD + hh0 + (lt&1))*16 + t0 + (lt>>1))*4096 + off;
    *(u16x8*)(Kf + base) = *(const u16x8*)(smem + gi);
    *(u16x8*)(Vf + base) = *(const u16x8*)(smem + 16384 + gi);
  }
}

// ---------------- attention: split-K (4 k-tiles/wave), L2-direct, tree merge ----
__global__ __launch_bounds__(256,2) void attn_k(const u16* __restrict__ kf,
                                                const u16* __restrict__ vf,
                                                u16* __restrict__ ao){
  __shared__ __align__(16) u16 sPm[16640];
  const int bid = blockIdx.x;
  const int qt = bid >> 6, bh = bid & 63;     // XCD = bid%8 = bh%8 -> K/V L2-resident
  const int b = bh >> 3, h = bh & 7;
  const u16* Kf = kf + (size_t)bh*16*4096;
  const u16* Vf = vf + (size_t)bh*16*4096;
  const int tid = threadIdx.x, w = tid>>6, lane = tid&63;
  const int lr = lane&15, lg = lane>>4;

  bf16x8 aq[4][2];
  #pragma unroll
  for (int g=0; g<4; ++g)
    #pragma unroll
    for (int ks=0; ks<2; ++ks){
      u16x8 v = *(const u16x8*)(Kf + (size_t)qt*4096 + (ks*4+g)*512 + lane*8);
      bf16x8 t;
      #pragma unroll
      for (int j=0;j<8;j++) t[j] = (short)f2bf(bf2f(v[j])*0.18033688f);
      aq[g][ks] = t;
    }

  f32x4 o[4][4] = {};
  float lsum[4][4] = {};

  for (int t=0; t<4; ++t){
    const int kt = w + t*4;
    const u16* Kt = Kf + (size_t)kt*4096;
    const u16* Vt = Vf + (size_t)kt*4096;
    bf16x8 bk[2][4];
    #pragma unroll
    for (int ks=0; ks<2; ++ks)
      #pragma unroll
      for (int nj=0; nj<4; ++nj)
        bk[ks][nj] = *(const bf16x8*)(Kt + (ks*4+nj)*512 + lane*8);
    #pragma unroll
    for (int g=0; g<4; ++g){
      f32x4 sc[4] = {};
      __builtin_amdgcn_s_setprio(1);
      #pragma unroll
      for (int ks=0; ks<2; ++ks)
        #pragma unroll
        for (int nj=0; nj<4; ++nj)
          sc[nj] = MFMA16(aq[g][ks], bk[ks][nj], sc[nj]);
      __builtin_amdgcn_s_setprio(0);
      const int wp = (w*4+g)*1024;
      #pragma unroll
      for (int nj=0; nj<4; ++nj){
        #pragma unroll
        for (int r=0; r<4; ++r){
          const float p = __builtin_amdgcn_exp2f(sc[nj][r]);
          lsum[g][r] += p;
          const int prow = lg*4 + r;
          sPm[wp + ((prow*64 + nj*16 + lr) ^ ((prow&7)<<3))]
              = (u16)(__float_as_uint(p)>>16);
        }
      }
    }
    asm volatile("s_waitcnt lgkmcnt(0)" ::: "memory");
    bf16x8 bv[2][4];
    #pragma unroll
    for (int ks=0; ks<2; ++ks)
      #pragma unroll
      for (int dj=0; dj<4; ++dj)
        bv[ks][dj] = *(const bf16x8*)(Vt + (ks*4+dj)*512 + lane*8);
    __builtin_amdgcn_s_setprio(1);
    #pragma unroll
    for (int g=0; g<4; ++g){
      const int wp = (w*4+g)*1024;
      #pragma unroll
      for (int ks=0; ks<2; ++ks){
        bf16x8 pa = *(const bf16x8*)(&sPm[wp + ((lr*64 + ks*32 + lg*8) ^ ((lr&7)<<3))]);
        #pragma unroll
        for (int dj=0; dj<4; ++dj)
          o[g][dj] = MFMA16(pa, bv[ks][dj], o[g][dj]);
      }
    }
    __builtin_amdgcn_s_setprio(0);
  }

  #pragma unroll
  for (int g=0; g<4; ++g)
    #pragma unroll
    for (int r=0; r<4; ++r){
      float s = lsum[g][r];
      s += __shfl_xor(s,1); s += __shfl_xor(s,2);
      s += __shfl_xor(s,4); s += __shfl_xor(s,8);
      lsum[g][r] = s;
    }

  __syncthreads();
  float* mrg = (float*)sPm;
  if (w & 1){
    float* R = mrg + (w>>1)*4160;
    #pragma unroll
    for (int g=0; g<4; ++g){
      #pragma unroll
      for (int dj=0; dj<4; ++dj)
        *(f32x4*)&R[(g*4+dj)*256 + lane*4] = o[g][dj];
      if (lr == 0)
        #pragma unroll
        for (int r=0; r<4; ++r) R[4096 + g*16 + lg*4 + r] = lsum[g][r];
    }
  }
  __syncthreads();
  if (!(w & 1)){
    float* R = mrg + (w>>1)*4160;
    #pragma unroll
    for (int g=0; g<4; ++g){
      #pragma unroll
      for (int dj=0; dj<4; ++dj)
        o[g][dj] += *(const f32x4*)&R[(g*4+dj)*256 + lane*4];
      #pragma unroll
      for (int r=0; r<4; ++r) lsum[g][r] += R[4096 + g*16 + lg*4 + r];
    }
  }
  if (w == 2){
    float* R = mrg + 4160;
    #pragma unroll
    for (int g=0; g<4; ++g){
      #pragma unroll
      for (int dj=0; dj<4; ++dj)
        *(f32x4*)&R[(g*4+dj)*256 + lane*4] = o[g][dj];
      if (lr == 0)
        #pragma unroll
        for (int r=0; r<4; ++r) R[4096 + g*16 + lg*4 + r] = lsum[g][r];
    }
  }
  __syncthreads();
  if (w == 0){
    float* R = mrg + 4160;
    #pragma unroll
    for (int g=0; g<4; ++g){
      #pragma unroll
      for (int dj=0; dj<4; ++dj)
        o[g][dj] += *(const f32x4*)&R[(g*4+dj)*256 + lane*4];
      #pragma unroll
      for (int r=0; r<4; ++r) lsum[g][r] += R[4096 + g*16 + lg*4 + r];
    }
    #pragma unroll
    for (int g=0; g<4; ++g){
      float inv[4];
      #pragma unroll
      for (int r=0; r<4; ++r) inv[r] = __builtin_amdgcn_rcpf(lsum[g][r]);
      const int i0 = qt*64 + g*16;
      #pragma unroll
      for (int dj=0; dj<4; ++dj)
        #pragma unroll
        for (int r=0; r<4; ++r){
          const int l = i0 + lg*4 + r;
          const int d = dj*16 + lr;
          ao[((size_t)(b*LTOK + l))*DMODEL + h*DHEAD + d] = f2bf(o[g][dj][r]*inv[r]);
        }
    }
  }
}

// ---------------- FC projection, 128x128 tile + bias + residual -----------------
__global__ __launch_bounds__(256) void fc_gemm(const u16* __restrict__ A,
                                               const u16* __restrict__ W,
                                               const float* __restrict__ bias,
                                               const u16* __restrict__ resid,
                                               u16* __restrict__ Y){
  __shared__ __align__(128) u16 smem[32768];
  const int m0 = blockIdx.x*128, n0 = blockIdx.y*128;
  const int tid = threadIdx.x, w = tid>>6, lane = tid&63;
  const int wr = w>>1, wc = w&1;
  const int lr = lane&15, lg = lane>>4;
  f32x4 acc[4][4] = {};
  stage128(A, m0, 0, smem, tid);
  stage128(W, n0, 0, smem + 16384, tid);
  int buf = 0;
  for (int kt=0; kt<8; ++kt){
    __syncthreads();
    if (kt < 7){
      stage128(A, m0, (kt+1)*64, smem + (buf^1)*8192, tid);
      stage128(W, n0, (kt+1)*64, smem + 16384 + (buf^1)*8192, tid);
    }
    const u16* sa = smem + buf*8192;
    const u16* sb = smem + 16384 + buf*8192;
    #pragma unroll
    for (int ks=0; ks<2; ++ks){
      bf16x8 af[4], bfr[4];
      #pragma unroll
      for (int mi=0; mi<4; ++mi){
        const int r = wr*64 + mi*16 + lr;
        af[mi] = *(const bf16x8*)(&sa[(r*64 + ks*32 + lg*8) ^ ((r&7)<<3)]);
      }
      #pragma unroll
      for (int nj=0; nj<4; ++nj){
        const int r = wc*64 + nj*16 + lr;
        bfr[nj] = *(const bf16x8*)(&sb[(r*64 + ks*32 + lg*8) ^ ((r&7)<<3)]);
      }
      #pragma unroll
      for (int mi=0; mi<4; ++mi)
        #pragma unroll
        for (int nj=0; nj<4; ++nj)
          acc[mi][nj] = MFMA16(af[mi], bfr[nj], acc[mi][nj]);
    }
    buf ^= 1;
  }
  __syncthreads();                 // arena free; stage f32 results (64KB exactly)
  float* lY = (float*)smem;
  #pragma unroll
  for (int mi=0; mi<4; ++mi)
    #pragma unroll
    for (int nj=0; nj<4; ++nj)
      #pragma unroll
      for (int r=0; r<4; ++r){
        const int rr = wr*64 + mi*16 + lg*4 + r;
        const int d  = wc*64 + nj*16 + lr;
        lY[rr*128 + (d ^ ((rr&7)<<2))] = acc[mi][nj][r];
      }
  __syncthreads();
  #pragma unroll
  for (int p=0; p<8; ++p){
    const int slot = p*256 + tid;
    const int row = slot>>4;
    const int ch  = (slot&15)*8;
    const int x   = (row&7)<<2;
    f32x4 ya = *(const f32x4*)&lY[row*128 + (ch ^ x)];
    f32x4 yb = *(const f32x4*)&lY[row*128 + ((ch+4) ^ x)];
    u16x8 rs = *(const u16x8*)(resid + (size_t)(m0+row)*DMODEL + n0 + ch);
    u16x8 o8;
    #pragma unroll
    for (int j=0;j<4;j++) o8[j]   = f2bf(ya[j] + bias[n0+ch+j]   + bf2f(rs[j]));
    #pragma unroll
    for (int j=0;j<4;j++) o8[j+4] = f2bf(yb[j] + bias[n0+ch+4+j] + bf2f(rs[j+4]));
    *(u16x8*)(Y + (size_t)(m0+row)*DMODEL + n0 + ch) = o8;
  }
}

// ---------------- LayerNorm over 512, one wave per row; fp32 out ----------------
__global__ __launch_bounds__(256) void ln_k(const u16* __restrict__ Y,
                                            const float* __restrict__ gamma,
                                            const float* __restrict__ beta,
                                            float* __restrict__ out){
  const int row = blockIdx.x*4 + (threadIdx.x>>6);
  const int lane = threadIdx.x&63;
  const u16* yr = Y + (size_t)row*DMODEL;
  u16x8 v = *(const u16x8*)(yr + lane*8);
  float x[8]; float s=0.f, sq=0.f;
  #pragma unroll
  for (int j=0;j<8;j++){ x[j]=bf2f(v[j]); s+=x[j]; sq+=x[j]*x[j]; }
  #pragma unroll
  for (int mk=1; mk<64; mk<<=1){ s += __shfl_xor(s,mk); sq += __shfl_xor(sq,mk); }
  const float mean = s*(1.f/DMODEL);
  float var = sq*(1.f/DMODEL) - mean*mean;
  const float rstd = rsqrtf(var + 1e-5f);
  float* po = out + (size_t)row*DMODEL + lane*8;
  #pragma unroll
  for (int j=0;j<8;j++){
    const int c = lane*8+j;
    po[j] = (x[j]-mean)*rstd*gamma[c] + beta[c];
  }
}

extern "C" void kernel_launch(void* const* d_in, const int* in_sizes, int n_in,
                              void* d_out, int out_size, void* d_ws, size_t ws_size,
                              hipStream_t stream){
  (void)in_sizes; (void)n_in; (void)out_size; (void)ws_size;
  const float* q      = (const float*)d_in[0];
  const float* w_qkvs = (const float*)d_in[1];
  const float* fc_w   = (const float*)d_in[2];
  const float* fc_b   = (const float*)d_in[3];
  const float* ln_g   = (const float*)d_in[4];
  const float* ln_b   = (const float*)d_in[5];
  float* out = (float*)d_out;
  char* ws = (char*)d_ws;
  u16* x_rm  = (u16*)(ws);                 // [8192][512] bf16
  u16* kfb   = (u16*)(ws + 8388608);       // fragment-major K/Q tiles
  u16* vfb   = (u16*)(ws + 16777216);      // fragment-major V tiles
  u16* ao    = (u16*)(ws + 25165824);      // [8192][512]
  u16* wqkvb = (u16*)(ws + 33554432);
  u16* wfcb  = (u16*)(ws + 34078720);
  u16* y0    = kfb;                        // reuse after attention

  prep_k<<<1280,256,0,stream>>>(q, x_rm, w_qkvs, wqkvb, fc_w, wfcb);
  qkv_gemm<<<dim3(64,4),256,0,stream>>>(x_rm, wqkvb, kfb, vfb);
  attn_k<<<1024,256,0,stream>>>(kfb, vfb, ao);
  fc_gemm<<<dim3(64,4),256,0,stream>>>(ao, wfcb, fc_b, x_rm, y0);
  ln_k<<<2048,256,0,stream>>>(y0, ln_g, ln_b, out);
}